// Round 1
// baseline (447.347 us; speedup 1.0000x reference)
//
#include <hip/hip_runtime.h>
#include <math.h>

#define N_NODES 100000
#define N_EDGES 1600000
#define D_IN 256
#define D_OUT 128

// ---- workspace layout (bytes) ------------------------------------------
// support : float[N_NODES*D_OUT]             @ 0           (51,200,000)
// counts  : int[N_NODES+1] (-> offsets)      @ 51,200,000  (   400,004)
// csr_ev  : int2[N_EDGES] {col, val-bits}    @ 51,600,008  (12,800,000)
// bsums   : int[SCAN_BLOCKS]                 @ 64,400,008  (       392)
// wt_hi   : short[128*256] W^T bf16-hi       @ 64,400,416  (    65,536)
// wt_lo   : short[128*256] W^T bf16-lo       @ 64,465,952  (    65,536)
// pos_e   : int[N_EDGES] lives in d_out (free until agg overwrites it)
#define OFF_SUPPORT 0
#define OFF_COUNTS  51200000
#define OFF_CSREV   51600008
#define OFF_BSUMS   64400008
#define OFF_WTHI    64400416
#define OFF_WTLO    64465952

#define SCAN_CHUNK  1024
#define SCAN_BLOCKS ((N_NODES + SCAN_CHUNK - 1) / SCAN_CHUNK)  // 98

#define GB 128                                   // GEMM block tile (nodes)
#define GEMM_BLOCKS ((N_NODES + GB - 1) / GB)    // 782
#define EDGE_BLOCKS ((N_EDGES + 255) / 256)      // 6250

typedef __attribute__((ext_vector_type(8))) short s8v;   // 8 bf16 = 4 VGPR
typedef __attribute__((ext_vector_type(4))) float f4v;   // mfma acc

__device__ __forceinline__ short f2bf(float x) {   // RNE fp32 -> bf16 bits
  unsigned u = __float_as_uint(x);
  unsigned r = u + 0x7FFF + ((u >> 16) & 1);
  return (short)(r >> 16);
}
__device__ __forceinline__ float bf2f(short h) {
  return __uint_as_float(((unsigned)(unsigned short)h) << 16);
}

// split a lane-local row of 8 fp32 into bf16 hi/lo fragments (in-register)
__device__ __forceinline__ void cvt8(float4 a, float4 b, s8v& h, s8v& l) {
  float f[8] = {a.x, a.y, a.z, a.w, b.x, b.y, b.z, b.w};
#pragma unroll
  for (int i = 0; i < 8; i++) {
    short hh = f2bf(f[i]);
    h[i] = hh;
    l[i] = f2bf(f[i] - bf2f(hh));
  }
}

// ---------------------------------------------------------------------------
// K0: W[k][n] fp32 -> wt_hi/wt_lo[n][k] bf16 split (once; 32K elems)
// ---------------------------------------------------------------------------
__global__ __launch_bounds__(256) void wconv_kernel(
    const float* __restrict__ W, short* __restrict__ wt_hi,
    short* __restrict__ wt_lo) {
  int idx = blockIdx.x * 256 + threadIdx.x;   // grid 128 -> 32768
  int k = idx >> 7;
  int n = idx & 127;
  float v = W[idx];
  short h = f2bf(v);
  wt_hi[n * 256 + k] = h;
  wt_lo[n * 256 + k] = f2bf(v - bf2f(h));
}

// ---------------------------------------------------------------------------
// Split-bf16 MFMA GEMM body, LDS-FREE version: support = X*W + b.
//   A: each element feeds exactly one lane's fragment -> load per-lane
//      straight from global (16 rows x fully-used cache lines per instr)
//      and do the hi/lo split in-register.  No staging, no barriers.
//   B: wt_hi/wt_lo = 128 KB, pre-converted, read by all 782 blocks ->
//      L2-resident; per-lane direct loads (64B contiguous per row).
// Fragment coordinates identical to the verified LDS version -> same math.
// ---------------------------------------------------------------------------
__device__ __forceinline__ void gemm_body(
    int gb, const float* __restrict__ input, const short* __restrict__ wt_hi,
    const short* __restrict__ wt_lo, const float* __restrict__ b,
    float* __restrict__ support) {
  const int t = threadIdx.x;
  const int lane = t & 63;
  const int wv = t >> 6;
  const int qm = lane & 15;
  const int quad = lane >> 4;
  const int node0 = gb * GB;

  const int row0 = node0 + wv * 32 + qm;   // m-tile 0 row for this lane
  const int row1 = row0 + 16;              // m-tile 1 row
  const bool ok0 = row0 < N_NODES;
  const bool ok1 = row1 < N_NODES;
  const float* a0p = input + (size_t)row0 * D_IN + quad * 8;
  const float* a1p = input + (size_t)row1 * D_IN + quad * 8;

  f4v acc[2][8];
#pragma unroll
  for (int mt = 0; mt < 2; mt++)
#pragma unroll
    for (int nt = 0; nt < 8; nt++) acc[mt][nt] = (f4v){0.f, 0.f, 0.f, 0.f};

  for (int k0 = 0; k0 < D_IN; k0 += 32) {
    float4 z = make_float4(0.f, 0.f, 0.f, 0.f);
    float4 v00 = z, v01 = z, v10 = z, v11 = z;
    if (ok0) {
      v00 = *(const float4*)(a0p + k0);
      v01 = *(const float4*)(a0p + k0 + 4);
    }
    if (ok1) {
      v10 = *(const float4*)(a1p + k0);
      v11 = *(const float4*)(a1p + k0 + 4);
    }
    s8v ah0, al0, ah1, al1;
    cvt8(v00, v01, ah0, al0);
    cvt8(v10, v11, ah1, al1);

    const int koff = k0 + quad * 8;
#pragma unroll
    for (int nt = 0; nt < 8; nt++) {
      const size_t bo = (size_t)(nt * 16 + qm) * 256 + koff;
      s8v bh = *(const s8v*)(wt_hi + bo);
      s8v bl = *(const s8v*)(wt_lo + bo);
      acc[0][nt] = __builtin_amdgcn_mfma_f32_16x16x32_bf16(ah0, bh, acc[0][nt], 0, 0, 0);
      acc[0][nt] = __builtin_amdgcn_mfma_f32_16x16x32_bf16(ah0, bl, acc[0][nt], 0, 0, 0);
      acc[0][nt] = __builtin_amdgcn_mfma_f32_16x16x32_bf16(al0, bh, acc[0][nt], 0, 0, 0);
      acc[1][nt] = __builtin_amdgcn_mfma_f32_16x16x32_bf16(ah1, bh, acc[1][nt], 0, 0, 0);
      acc[1][nt] = __builtin_amdgcn_mfma_f32_16x16x32_bf16(ah1, bl, acc[1][nt], 0, 0, 0);
      acc[1][nt] = __builtin_amdgcn_mfma_f32_16x16x32_bf16(al1, bh, acc[1][nt], 0, 0, 0);
    }
  }

  float bias[8];
#pragma unroll
  for (int nt = 0; nt < 8; nt++) bias[nt] = b[nt * 16 + qm];
#pragma unroll
  for (int mt = 0; mt < 2; mt++) {
#pragma unroll
    for (int nt = 0; nt < 8; nt++) {
      int col = nt * 16 + qm;
#pragma unroll
      for (int r = 0; r < 4; r++) {
        int node = node0 + wv * 32 + mt * 16 + quad * 4 + r;
        if (node < N_NODES)
          support[(size_t)node * D_OUT + col] = acc[mt][nt][r] + bias[nt];
      }
    }
  }
}

// K1: FULL GEMM || FULL hist (GEMM blocks first to seed the CUs)
__global__ __launch_bounds__(256) void gemm_hist_kernel(
    const float* __restrict__ input, const short* __restrict__ wt_hi,
    const short* __restrict__ wt_lo, const float* __restrict__ b,
    float* __restrict__ support, const int* __restrict__ erow,
    int* __restrict__ counts, int* __restrict__ pos_e) {
  if (blockIdx.x < GEMM_BLOCKS) {
    gemm_body(blockIdx.x, input, wt_hi, wt_lo, b, support);
  } else {
    int e = (blockIdx.x - GEMM_BLOCKS) * 256 + threadIdx.x;
    if (e < N_EDGES) pos_e[e] = atomicAdd(&counts[erow[e]], 1);
  }
}

// K2: atomic-free CSR bucket scatter
__global__ __launch_bounds__(256) void build_kernel(
    const int* __restrict__ erow, const int* __restrict__ ecol,
    const float* __restrict__ eval, const int* __restrict__ offsets,
    const int* __restrict__ pos_e, int2* __restrict__ csr_ev) {
  int e = blockIdx.x * 256 + threadIdx.x;
  if (e < N_EDGES) {
    int idx = offsets[erow[e]] + pos_e[e];
    csr_ev[idx] = make_int2(ecol[e], __float_as_int(eval[e]));
  }
}

// ---------------------------------------------------------------------------
// 3-phase exclusive scan over counts (verified round 2)
// ---------------------------------------------------------------------------
__global__ __launch_bounds__(256) void scan_phase1(const int* __restrict__ counts,
                                                   int* __restrict__ bsums) {
  __shared__ int ts[256];
  int t = threadIdx.x;
  int idx0 = blockIdx.x * SCAN_CHUNK + t * 4;
  int s = 0;
#pragma unroll
  for (int i = 0; i < 4; i++)
    if (idx0 + i < N_NODES) s += counts[idx0 + i];
  ts[t] = s;
  __syncthreads();
#pragma unroll
  for (int off = 128; off > 0; off >>= 1) {
    if (t < off) ts[t] += ts[t + off];
    __syncthreads();
  }
  if (t == 0) bsums[blockIdx.x] = ts[0];
}

__global__ __launch_bounds__(128) void scan_phase2(int* __restrict__ bsums) {
  __shared__ int s[128];
  int t = threadIdx.x;
  int v = (t < SCAN_BLOCKS) ? bsums[t] : 0;
  s[t] = v;
  __syncthreads();
#pragma unroll
  for (int off = 1; off < 128; off <<= 1) {
    int x = (t >= off) ? s[t - off] : 0;
    __syncthreads();
    s[t] += x;
    __syncthreads();
  }
  if (t < SCAN_BLOCKS) bsums[t] = s[t] - v;  // exclusive
}

__global__ __launch_bounds__(256) void scan_phase3(int* __restrict__ counts,
                                                   const int* __restrict__ bsums) {
  __shared__ int ts[256];
  int t = threadIdx.x;
  int b = blockIdx.x;
  int idx0 = b * SCAN_CHUNK + t * 4;
  int v[4];
  int s = 0;
#pragma unroll
  for (int i = 0; i < 4; i++) {
    v[i] = (idx0 + i < N_NODES) ? counts[idx0 + i] : 0;
    s += v[i];
  }
  ts[t] = s;
  __syncthreads();
#pragma unroll
  for (int off = 1; off < 256; off <<= 1) {
    int x = (t >= off) ? ts[t - off] : 0;
    __syncthreads();
    ts[t] += x;
    __syncthreads();
  }
  int run = bsums[b] + ts[t] - s;
#pragma unroll
  for (int i = 0; i < 4; i++) {
    int idx = idx0 + i;
    if (idx < N_NODES) counts[idx] = run;
    run += v[i];
  }
  if (b == 0 && t == 0) counts[N_NODES] = N_EDGES;
}

// ---------------------------------------------------------------------------
// Gather-aggregate + fused tanh.  32 lanes x float4 per row (vs 128 x scalar):
// 4x fewer load instructions, 8x16B gathers in flight per lane, float4 store.
// 256-thread block handles 8 rows; grid 12500.
// ---------------------------------------------------------------------------
__global__ __launch_bounds__(256) void agg_kernel(
    const int* __restrict__ offsets, const int2* __restrict__ csr_ev,
    const float* __restrict__ support, float* __restrict__ out) {
  int r = blockIdx.x * 8 + (threadIdx.x >> 5);
  int l4 = (threadIdx.x & 31) * 4;          // feature quad
  int beg = offsets[r];
  int end = offsets[r + 1];
  float4 acc = make_float4(0.f, 0.f, 0.f, 0.f);
  int j = beg;
  for (; j + 8 <= end; j += 8) {
    int2 e[8];
    float4 s[8];
#pragma unroll
    for (int u = 0; u < 8; u++) e[u] = csr_ev[j + u];
#pragma unroll
    for (int u = 0; u < 8; u++)
      s[u] = *(const float4*)(support + (size_t)e[u].x * D_OUT + l4);
#pragma unroll
    for (int u = 0; u < 8; u++) {
      float v = __int_as_float(e[u].y);
      acc.x = fmaf(v, s[u].x, acc.x);
      acc.y = fmaf(v, s[u].y, acc.y);
      acc.z = fmaf(v, s[u].z, acc.z);
      acc.w = fmaf(v, s[u].w, acc.w);
    }
  }
  for (; j < end; j++) {
    int2 ev = csr_ev[j];
    float4 s = *(const float4*)(support + (size_t)ev.x * D_OUT + l4);
    float v = __int_as_float(ev.y);
    acc.x = fmaf(v, s.x, acc.x);
    acc.y = fmaf(v, s.y, acc.y);
    acc.z = fmaf(v, s.z, acc.z);
    acc.w = fmaf(v, s.w, acc.w);
  }
  *(float4*)(out + (size_t)r * D_OUT + l4) =
      make_float4(tanhf(acc.x), tanhf(acc.y), tanhf(acc.z), tanhf(acc.w));
}

extern "C" void kernel_launch(void* const* d_in, const int* in_sizes, int n_in,
                              void* d_out, int out_size, void* d_ws, size_t ws_size,
                              hipStream_t stream) {
  const float* input = (const float*)d_in[0];
  const int* erow = (const int*)d_in[1];
  const int* ecol = (const int*)d_in[2];
  const float* eval = (const float*)d_in[3];
  const float* W = (const float*)d_in[4];
  const float* b = (const float*)d_in[5];
  float* out = (float*)d_out;

  char* ws = (char*)d_ws;
  float* support = (float*)(ws + OFF_SUPPORT);
  int* counts = (int*)(ws + OFF_COUNTS);  // becomes offsets after scan
  int2* csr_ev = (int2*)(ws + OFF_CSREV);
  int* bsums = (int*)(ws + OFF_BSUMS);
  short* wt_hi = (short*)(ws + OFF_WTHI);
  short* wt_lo = (short*)(ws + OFF_WTLO);
  int* pos_e = (int*)d_out;  // d_out as scratch; agg overwrites it last

  // K0: convert W once (transposed bf16 hi/lo)
  hipLaunchKernelGGL(wconv_kernel, dim3((D_IN * D_OUT) / 256), dim3(256), 0,
                     stream, W, wt_hi, wt_lo);
  hipMemsetAsync(ws + OFF_COUNTS, 0, (size_t)(N_NODES + 1) * 4, stream);

  // K1: full MFMA-GEMM || full histogram
  hipLaunchKernelGGL(gemm_hist_kernel, dim3(GEMM_BLOCKS + EDGE_BLOCKS),
                     dim3(256), 0, stream, input, wt_hi, wt_lo, b, support,
                     erow, counts, pos_e);
  // exclusive scan: counts -> offsets
  hipLaunchKernelGGL(scan_phase1, dim3(SCAN_BLOCKS), dim3(256), 0, stream,
                     counts, bsums);
  hipLaunchKernelGGL(scan_phase2, dim3(1), dim3(128), 0, stream, bsums);
  hipLaunchKernelGGL(scan_phase3, dim3(SCAN_BLOCKS), dim3(256), 0, stream,
                     counts, bsums);
  // K2: atomic-free CSR bucket scatter
  hipLaunchKernelGGL(build_kernel, dim3(EDGE_BLOCKS), dim3(256), 0, stream,
                     erow, ecol, eval, counts, pos_e, csr_ev);
  // out = tanh(A_csr * support)
  hipLaunchKernelGGL(agg_kernel, dim3(N_NODES / 8), dim3(256), 0, stream,
                     counts, csr_ev, support, out);
}